// Round 5
// baseline (265.890 us; speedup 1.0000x reference)
//
#include <hip/hip_runtime.h>
#include <float.h>
#include <stdint.h>

// Problem constants: B=64, H=W=32, C=256, D=H*W=1024, K=1024
#define B_   64
#define C_   256
#define D_   1024
#define K_   1024
#define M_   16384
#define NX_  16777216          // B*D*C = M*D
#define DISC_OFF NX_
#define LOSS_OFF (NX_ + M_)

typedef _Float16 h8 __attribute__((ext_vector_type(8)));
typedef float    f4 __attribute__((ext_vector_type(4)));

// Power-of-2 split scales (exact). acc = 2^20 * dot.
#define XSCALE 512.0f
#define ESCALE 2048.0f
#define DOT_UNSCALE_2 (2.0f / 1048576.0f)

// d_ws layout (float offsets).
#define WS_EH  0          // 1M fp16 = 524288 floats
#define WS_EL  524288
#define WS_CN  1048576    // 1024
#define WS_PCN 1049600    // 128*1024 = 131072
#define WS_PV  1180672    // 16384*4 = 65536
#define WS_PI  1246208    // 16384*4 = 65536

__device__ __forceinline__ void async16(const _Float16* g, _Float16* l) {
    __builtin_amdgcn_global_load_lds(
        (const __attribute__((address_space(1))) unsigned int*)g,
        (__attribute__((address_space(3))) unsigned int*)l, 16, 0, 0);
}

// ---------------------------------------------------------------------------
// Fused split kernel. Blocks [0,512): E -> fragment-tiled fp16 hi/lo planes
// [nt][kt][lane][8] + colnorm partials. Blocks [512,8704): x -> same layout.
// ---------------------------------------------------------------------------
__global__ __launch_bounds__(256) void split_kernel(const float* __restrict__ x,
                                                    const float* __restrict__ E,
                                                    _Float16* __restrict__ Xh,
                                                    _Float16* __restrict__ Xl,
                                                    _Float16* __restrict__ Eh,
                                                    _Float16* __restrict__ El,
                                                    float* __restrict__ pcn) {
    const int bid = blockIdx.x;
    if (bid < 512) {
        // ---- E split + colnorm partials ----
        const int tid = bid * 256 + threadIdx.x;      // [0, 131072)
        const int n   = tid & 1023;
        const int o   = tid >> 10;                    // k-octet [0,128)
        const int d0  = o * 8;
        h8 hh, ll;
        float s = 0.f;
        #pragma unroll
        for (int i = 0; i < 8; ++i) {
            const float v = E[(size_t)(d0 + i) * K_ + n];
            s = fmaf(v, v, s);
            const float vs = v * ESCALE;
            const _Float16 h = (_Float16)vs;
            hh[i] = h;
            ll[i] = (_Float16)(vs - (float)h);
        }
        pcn[o * K_ + n] = s;
        const int nt   = n >> 4;
        const int kt   = o >> 2;
        const int lane = (n & 15) + (o & 3) * 16;
        const size_t off = ((size_t)(nt * 32 + kt) * 64 + lane) * 8;
        *(h8*)(Eh + off) = hh;
        *(h8*)(El + off) = ll;
    } else {
        // ---- x split ----
        const int tid = (bid - 512) * 256 + threadIdx.x;  // [0, 2097152)
        const int m   = tid & 16383;
        const int o   = tid >> 14;                        // [0,128)
        const int b   = m >> 8, c = m & 255;
        const int d0  = o * 8;
        const float* xp = x + ((size_t)(b * 1024 + d0) * 256) + c;
        h8 hh, ll;
        #pragma unroll
        for (int i = 0; i < 8; ++i) {
            const float v  = xp[(size_t)i * 256];
            const float vs = v * XSCALE;
            const _Float16 h = (_Float16)vs;
            hh[i] = h;
            ll[i] = (_Float16)(vs - (float)h);
        }
        const int mt   = m >> 4;
        const int kt   = o >> 2;
        const int lane = (m & 15) + (o & 3) * 16;
        const size_t off = ((size_t)(mt * 32 + kt) * 64 + lane) * 8;
        *(h8*)(Xh + off) = hh;
        *(h8*)(Xl + off) = ll;
    }
}

// colnorm: sum the 128 partials per column; zero the loss slot.
__global__ __launch_bounds__(256) void colnorm2_kernel(const float* __restrict__ pcn,
                                                       float* __restrict__ cn,
                                                       float* __restrict__ loss_slot) {
    const int k = blockIdx.x * 256 + threadIdx.x;
    float s = 0.f;
    for (int i = 0; i < 128; ++i) s += pcn[i * K_ + k];
    cn[k] = s;
    if (k == 0) *loss_slot = 0.0f;
}

// ---------------------------------------------------------------------------
// Split-fp16 MFMA distance GEMM + per-block argmin.
// 128x256 tile, 512 threads (8 waves, each 64x64), BK=32.
// A: LDS double-buffer via global_load_lds (16 KB/step).
// B: direct global->VGPR fragment loads (L2-resident), register double-buffer.
// One barrier per k-step; LDS traffic is A-only -> MFMA-bound.
// Grid 512 = 128 rt x 4 ct (consecutive blocks share rt -> A L3 locality).
// ---------------------------------------------------------------------------
__global__ __launch_bounds__(512, 2) void gemm_argmin_kernel(
        const _Float16* __restrict__ Xh, const _Float16* __restrict__ Xl,
        const _Float16* __restrict__ Eh, const _Float16* __restrict__ El,
        const float* __restrict__ cn,
        float* __restrict__ pV, int* __restrict__ pI) {
    __shared__ _Float16 Ab[2][16 * 512];   // [buf][plane*8+mt][512]  16 KB each
    __shared__ float cV[128 * 4];
    __shared__ int   cI[128 * 4];

    const int t    = threadIdx.x;
    const int rt   = blockIdx.x >> 2;     // 0..127
    const int ct   = blockIdx.x & 3;      // 0..3
    const int wave = t >> 6, lane = t & 63;
    const int lo16 = lane & 15, hi4 = lane >> 4;
    const int mq   = (wave & 1) * 64;
    const int nq   = (wave >> 1) * 64;    // 0,64,128,192
    const int mt0  = rt * 8, nt0 = ct * 16;
    const int n0g  = ct * 256;
    const int amq  = mq >> 4;             // A tile base within buffer
    const int lane8 = lane * 8;

    // A DMA: 16 chunks/k-step (2 planes x 8 mt), 2 per wave.
    const _Float16* srcA[2];
    _Float16* dstA[2][2];
    #pragma unroll
    for (int i = 0; i < 2; ++i) {
        const int id = wave * 2 + i;
        const int plane = id >> 3, mt = id & 7;
        srcA[i] = (plane ? Xl : Xh) + ((size_t)(mt0 + mt) * 32) * 512 + lane8;
        dstA[0][i] = &Ab[0][(plane * 8 + mt) * 512 + lane8];
        dstA[1][i] = &Ab[1][(plane * 8 + mt) * 512 + lane8];
    }

    // B fragment sources: 8 per wave per k-step (4 tn x 2 planes).
    const _Float16* srcB[2][4];
    #pragma unroll
    for (int tn = 0; tn < 4; ++tn) {
        const int nt = nt0 + (nq >> 4) + tn;
        srcB[0][tn] = Eh + ((size_t)nt * 32) * 512 + lane8;
        srcB[1][tn] = El + ((size_t)nt * 32) * 512 + lane8;
    }

    f4 acc[4][4];
    const f4 zero = {0.f, 0.f, 0.f, 0.f};
    #pragma unroll
    for (int i = 0; i < 4; ++i)
        #pragma unroll
        for (int j = 0; j < 4; ++j) acc[i][j] = zero;

    h8 Bf0[2][4], Bf1[2][4];

    // ---- prologue: k-step 0 ----
    #pragma unroll
    for (int i = 0; i < 2; ++i) async16(srcA[i], dstA[0][i]);
    #pragma unroll
    for (int p = 0; p < 2; ++p)
        #pragma unroll
        for (int tn = 0; tn < 4; ++tn) Bf0[p][tn] = *(const h8*)(srcB[p][tn]);

    #define COMPUTE(ABUF, BF)                                                            \
        do {                                                                             \
            _Pragma("unroll")                                                            \
            for (int tm = 0; tm < 4; ++tm) {                                             \
                const h8 Ah = *(const h8*)&(ABUF)[(amq + tm) * 512 + lane8];             \
                const h8 Al = *(const h8*)&(ABUF)[(8 + amq + tm) * 512 + lane8];         \
                _Pragma("unroll")                                                        \
                for (int tn = 0; tn < 4; ++tn) {                                         \
                    acc[tm][tn] = __builtin_amdgcn_mfma_f32_16x16x32_f16(Ah, (BF)[0][tn], acc[tm][tn], 0, 0, 0); \
                    acc[tm][tn] = __builtin_amdgcn_mfma_f32_16x16x32_f16(Ah, (BF)[1][tn], acc[tm][tn], 0, 0, 0); \
                    acc[tm][tn] = __builtin_amdgcn_mfma_f32_16x16x32_f16(Al, (BF)[0][tn], acc[tm][tn], 0, 0, 0); \
                }                                                                        \
            }                                                                            \
        } while (0)

    for (int s = 0; s < 32; s += 2) {
        // ---- even step s: compute Ab[0]/Bf0; prefetch s+1 -> Ab[1]/Bf1 ----
        __syncthreads();                   // drains DMA for Ab[0]; Ab[1] free
        {
            #pragma unroll
            for (int i = 0; i < 2; ++i) async16(srcA[i] + (size_t)(s + 1) * 512, dstA[1][i]);
            #pragma unroll
            for (int p = 0; p < 2; ++p)
                #pragma unroll
                for (int tn = 0; tn < 4; ++tn)
                    Bf1[p][tn] = *(const h8*)(srcB[p][tn] + (size_t)(s + 1) * 512);
        }
        COMPUTE(Ab[0], Bf0);
        // ---- odd step s+1: compute Ab[1]/Bf1; prefetch s+2 -> Ab[0]/Bf0 ----
        __syncthreads();
        if (s + 2 < 32) {
            #pragma unroll
            for (int i = 0; i < 2; ++i) async16(srcA[i] + (size_t)(s + 2) * 512, dstA[0][i]);
            #pragma unroll
            for (int p = 0; p < 2; ++p)
                #pragma unroll
                for (int tn = 0; tn < 4; ++tn)
                    Bf0[p][tn] = *(const h8*)(srcB[p][tn] + (size_t)(s + 2) * 512);
        }
        COMPUTE(Ab[1], Bf1);
    }
    #undef COMPUTE

    // ---- epilogue: per-row argmin over this block's 256 cols ----
    float cnv[4];
    #pragma unroll
    for (int tn = 0; tn < 4; ++tn) cnv[tn] = cn[n0g + nq + tn * 16 + lo16];

    #pragma unroll
    for (int tm = 0; tm < 4; ++tm) {
        #pragma unroll
        for (int r = 0; r < 4; ++r) {
            float bv = FLT_MAX;
            int   bi = 0;
            #pragma unroll
            for (int tn = 0; tn < 4; ++tn) {   // ascending col => first-index tie-break
                const float v = cnv[tn] - acc[tm][tn][r] * DOT_UNSCALE_2;
                if (v < bv) { bv = v; bi = nq + tn * 16 + lo16; }
            }
            #pragma unroll
            for (int msk = 1; msk < 16; msk <<= 1) {
                const float ov = __shfl_xor(bv, msk, 64);
                const int   oi = __shfl_xor(bi, msk, 64);
                if (ov < bv || (ov == bv && oi < bi)) { bv = ov; bi = oi; }
            }
            if (lo16 == 0) {
                const int row = mq + tm * 16 + hi4 * 4 + r;
                const int g   = wave >> 1;     // n-quadrant index (ascending n)
                cV[row * 4 + g] = bv;
                cI[row * 4 + g] = bi;
            }
        }
    }
    __syncthreads();
    if (t < 128) {
        float bv = FLT_MAX;
        int   bi = 0;
        #pragma unroll
        for (int g = 0; g < 4; ++g) {          // ascending n-base, strict <
            const float v = cV[t * 4 + g];
            const int   i = cI[t * 4 + g];
            if (v < bv || (v == bv && i < bi)) { bv = v; bi = i; }
        }
        const int row = rt * 128 + t;
        pV[row * 4 + ct] = bv;
        pI[row * 4 + ct] = n0g + bi;
    }
}

// ---------------------------------------------------------------------------
// Final argmin across the 4 col-tiles (ascending, numpy tie-break).
// ---------------------------------------------------------------------------
__global__ __launch_bounds__(256) void reduce_kernel(const float* __restrict__ pV,
                                                     const int* __restrict__ pI,
                                                     float* __restrict__ disc) {
    const int rid = blockIdx.x * 256 + threadIdx.x;
    float bv = FLT_MAX;
    int   bi = 0;
    #pragma unroll
    for (int c = 0; c < 4; ++c) {
        const float v = pV[rid * 4 + c];
        const int   i = pI[rid * 4 + c];
        if (v < bv || (v == bv && i < bi)) { bv = v; bi = i; }
    }
    disc[rid] = (float)bi;
}

// ---------------------------------------------------------------------------
// finalize: one block per d. E row d staged in LDS (4 KB), gather via ds_read.
// q = x + (e - x); loss += 1.25*mean((x-e)^2). Fully coalesced x/q streams.
// ---------------------------------------------------------------------------
__global__ __launch_bounds__(256) void finalize_kernel(const float* __restrict__ x,
                                                       const float* __restrict__ E,
                                                       const float* __restrict__ discf,
                                                       float* __restrict__ out,
                                                       float* __restrict__ loss) {
    __shared__ float Erow[1024];
    const int t = threadIdx.x;
    const int d = blockIdx.x;
    *(float4*)&Erow[t * 4] = *(const float4*)(E + (size_t)d * K_ + t * 4);
    __syncthreads();

    const int bl = t >> 6;           // wave id -> b offset
    const int c4 = (t & 63) * 4;
    float lsum = 0.f;
    #pragma unroll 4
    for (int bg = 0; bg < 64; bg += 4) {
        const int b = bg + bl;
        const float4 id4 = *(const float4*)(discf + b * 256 + c4);
        const size_t xoff = ((size_t)(b * 1024 + d) << 8) + c4;
        const float4 xv = *(const float4*)(x + xoff);
        const float e0 = Erow[(int)id4.x];
        const float e1 = Erow[(int)id4.y];
        const float e2 = Erow[(int)id4.z];
        const float e3 = Erow[(int)id4.w];
        float4 qv;
        qv.x = xv.x + (e0 - xv.x);
        qv.y = xv.y + (e1 - xv.y);
        qv.z = xv.z + (e2 - xv.z);
        qv.w = xv.w + (e3 - xv.w);
        *(float4*)(out + xoff) = qv;
        const float d0 = xv.x - e0, d1 = xv.y - e1, d2 = xv.z - e2, d3 = xv.w - e3;
        lsum += fmaf(d0, d0, fmaf(d1, d1, fmaf(d2, d2, d3 * d3)));
    }

    #pragma unroll
    for (int off = 32; off > 0; off >>= 1)
        lsum += __shfl_down(lsum, off);
    __shared__ float wsum[4];
    if ((t & 63) == 0) wsum[t >> 6] = lsum;
    __syncthreads();
    if (t == 0) {
        const float s = (wsum[0] + wsum[1]) + (wsum[2] + wsum[3]);
        atomicAdd(loss, s * (1.25f / 16777216.0f));
    }
}

// ---------------------------------------------------------------------------
extern "C" void kernel_launch(void* const* d_in, const int* in_sizes, int n_in,
                              void* d_out, int out_size, void* d_ws, size_t ws_size,
                              hipStream_t stream) {
    (void)in_sizes; (void)n_in; (void)out_size; (void)ws_size;
    const float* x = (const float*)d_in[0];   // (64,32,32,256) f32
    const float* E = (const float*)d_in[1];   // (1024,1024)    f32
    float* out = (float*)d_out;
    float* ws  = (float*)d_ws;

    _Float16* Eh = (_Float16*)(ws + WS_EH);
    _Float16* El = (_Float16*)(ws + WS_EL);
    float* cn    = ws + WS_CN;
    float* pcn   = ws + WS_PCN;
    float* pV    = ws + WS_PV;
    int*   pI    = (int*)(ws + WS_PI);

    _Float16* Xh = (_Float16*)out;            // q-region scratch (overwritten by finalize)
    _Float16* Xl = (_Float16*)out + NX_;
    float* disc  = out + DISC_OFF;
    float* loss  = out + LOSS_OFF;

    split_kernel   <<<8704, 256, 0, stream>>>(x, E, Xh, Xl, Eh, El, pcn);
    colnorm2_kernel<<<4,    256, 0, stream>>>(pcn, cn, loss);
    gemm_argmin_kernel<<<512, 512, 0, stream>>>(Xh, Xl, Eh, El, cn, pV, pI);
    reduce_kernel  <<<64,   256, 0, stream>>>(pV, pI, disc);
    finalize_kernel<<<1024, 256, 0, stream>>>(x, E, disc, out, loss);
}